// Round 8
// baseline (157.509 us; speedup 1.0000x reference)
//
#include <hip/hip_runtime.h>
#include <math.h>

constexpr int kH = 64, kW = 128, kB = 2, kS = 4;
constexpr int kNP = kH * kW;          // 8192 points per set
constexpr int kPairs = kB * kS;       // 8
constexpr int kDirs = kPairs * 2;     // 16
constexpr float kPen = 32768.0f;      // exclusion penalty (bf16-exact pow2)
constexpr float kPi = 3.14159265358979323846f;
constexpr float kFovUp = 3.0f * kPi / 180.0f;
constexpr float kFovDown = -25.0f * kPi / 180.0f;

typedef short short8 __attribute__((ext_vector_type(8)));
typedef unsigned short ushort8 __attribute__((ext_vector_type(8)));
typedef float floatx16 __attribute__((ext_vector_type(16)));

// nn tiling with mfma_f32_32x32x16_bf16 (1024 evals/inst):
// block = 256 (4 waves); per wave 8 query tiles of 32 = 256 queries
// -> 1024 queries/block. Candidate chunk = 1024 staged in LDS (32 KB).
constexpr int NCC = 8;                // candidate chunks
constexpr int CCH = kNP / NCC;        // 1024 candidates
constexpr int NQB = 8;                // query blocks (8192/1024)
// grid = 16 * 8 * 8 = 1024 blocks, 64 blocks per dir

// ws layout (float offsets)
// cf   : [kDirs][kNP][16] bf16 -> 1048576 floats @ 0    (4 MB)
//        grouped: per 32 candidates: [32 x lo8][32 x hi8] (512 shorts/group)
// pts  : [kDirs][kNP] float4   -> 524288 @ 1048576      (2 MB)
// min  : [kDirs][kNP] u32      -> 131072 @ 1572864      (0.5 MB)
// mval : [kDirs] f32           -> 16  @ 1703936
// dcnt : [kDirs] u32           -> 16  @ 1703952
// acnt : u32                   -> 1   @ 1703968
constexpr size_t OFF_PTS = 1048576;
constexpr size_t OFF_MIN = 1572864;
constexpr size_t OFF_MVAL = 1703936;
constexpr size_t OFF_DCNT = 1703952;
constexpr size_t OFF_ACNT = 1703968;

__device__ __forceinline__ unsigned short f2bf(float v) {
  unsigned u = __float_as_uint(v);
  unsigned r = u + 0x7FFFu + ((u >> 16) & 1u);   // RNE
  return (unsigned short)(r >> 16);
}
__device__ __forceinline__ float bf2f(unsigned short b) {
  return __uint_as_float(((unsigned)b) << 16);
}

// Candidate record F (16 bf16, K-halves: lanes0-31 = k0..7, lanes32-63 = k8..15)
// pairs with query record G:
//  k : 0    1    2    3    4    5    6    7  | 8    9    10   11   12-15
//  F : Xh   Xl   Xh   Yh   Yl   Yh   Zh   Zl | Zh   Ch   Cl   Cl2  0
//  G : xh   xh   xl   yh   yh   yl   zh   zh | zl   1    1    1    0
// sum_k F*G = X*x + Y*y + Z*z + ct  (drops only lo*lo terms ~2e-4)
__global__ __launch_bounds__(256) void prep_kernel(
    const float* __restrict__ rv, const float* __restrict__ tgt,
    unsigned short* __restrict__ cf, float4* __restrict__ pts,
    unsigned* __restrict__ minarr, float* __restrict__ mval,
    unsigned* __restrict__ dcnt, unsigned* __restrict__ acnt) {
  int idx = blockIdx.x * 256 + threadIdx.x;   // [0, kPairs*kNP)
  int p = idx >> 13;
  int k = idx & (kNP - 1);
  int h = k >> 7;
  int w = k & 127;

  float r = rv[idx];
  float pitch = (1.0f - (h + 0.5f) * (1.0f / kH)) * (kFovUp - kFovDown) + kFovDown;
  float yaw = -(((w + 0.5f) * (1.0f / kW)) * 2.0f - 1.0f) * kPi;
  float cp = __cosf(pitch), sp = __sinf(pitch);
  float cy = __cosf(yaw), sy = __sinf(yaw);
  float px = r * cp * cy, py = r * cp * sy, pz = r * sp;
  float mo = (r > 0.0f) ? 1.0f : 0.0f;

  const float* tb = tgt + (size_t)p * 4 * kNP;
  float mt = (tb[k] > 0.0f) ? 1.0f : 0.0f;
  float tx = tb[kNP + k], ty = tb[2 * kNP + k], tz = tb[3 * kNP + k];

  float no = px * px + py * py + pz * pz;
  float nt = tx * tx + ty * ty + tz * tz;
  float co = no + kPen * (1.0f - mo);
  float ct = nt + kPen * (1.0f - mt);

  int d0 = 2 * p, d1 = d0 + 1;
  // pts.w < 16384 <=> valid query, and equals |p|^2 then.
  pts[(size_t)d0 * kNP + k] = make_float4(px, py, pz, co);
  pts[(size_t)d1 * kNP + k] = make_float4(tx, ty, tz, ct);

  // candidate records (dir0 candidates = tgt pts; dir1 candidates = rv pts)
  {
    float X = -2.0f * tx, Y = -2.0f * ty, Z = -2.0f * tz;
    unsigned short Xh = f2bf(X), Yh = f2bf(Y), Zh = f2bf(Z);
    unsigned short Xl = f2bf(X - bf2f(Xh));
    unsigned short Yl = f2bf(Y - bf2f(Yh));
    unsigned short Zl = f2bf(Z - bf2f(Zh));
    unsigned short Ch = f2bf(ct);
    float c1 = ct - bf2f(Ch);
    unsigned short Cl = f2bf(c1);
    unsigned short Cl2 = f2bf(c1 - bf2f(Cl));
    size_t base = (size_t)d0 * kNP * 16 + (size_t)(k >> 5) * 512 + (size_t)(k & 31) * 8;
    *(ushort8*)(cf + base) = (ushort8){Xh, Xl, Xh, Yh, Yl, Yh, Zh, Zl};
    *(ushort8*)(cf + base + 256) = (ushort8){Zh, Ch, Cl, Cl2, 0, 0, 0, 0};
  }
  {
    float X = -2.0f * px, Y = -2.0f * py, Z = -2.0f * pz;
    unsigned short Xh = f2bf(X), Yh = f2bf(Y), Zh = f2bf(Z);
    unsigned short Xl = f2bf(X - bf2f(Xh));
    unsigned short Yl = f2bf(Y - bf2f(Yh));
    unsigned short Zl = f2bf(Z - bf2f(Zh));
    unsigned short Ch = f2bf(co);
    float c1 = co - bf2f(Ch);
    unsigned short Cl = f2bf(c1);
    unsigned short Cl2 = f2bf(c1 - bf2f(Cl));
    size_t base = (size_t)d1 * kNP * 16 + (size_t)(k >> 5) * 512 + (size_t)(k & 31) * 8;
    *(ushort8*)(cf + base) = (ushort8){Xh, Xl, Xh, Yh, Yl, Yh, Zh, Zl};
    *(ushort8*)(cf + base + 256) = (ushort8){Zh, Ch, Cl, Cl2, 0, 0, 0, 0};
  }

  minarr[(size_t)d0 * kNP + k] = 0xFFFFFFFFu;
  minarr[(size_t)d1 * kNP + k] = 0xFFFFFFFFu;
  if (idx < kDirs) { dcnt[idx] = 0u; mval[idx] = 0.0f; }
  if (idx == kDirs) *acnt = 0u;
}

__global__ __launch_bounds__(256, 4) void nn_kernel(
    const unsigned short* __restrict__ cf, const float4* __restrict__ pts,
    unsigned* __restrict__ minarr, float* __restrict__ mval,
    unsigned* __restrict__ dcnt, unsigned* __restrict__ acnt,
    float* __restrict__ out) {
  __shared__ unsigned short sc[CCH * 16];   // 32 KB candidate records
  __shared__ unsigned s_ticket;
  __shared__ float sw[4], sm[4];

  int bid = blockIdx.x;
  int d = bid >> 6;            // / (NQB*NCC) = 64 blocks per dir
  int qb = (bid >> 3) & 7;
  int ch = bid & 7;
  int t = threadIdx.x;

  // stage chunk: 16384 shorts (32 groups of [32 x lo8][32 x hi8])
  const float4* src = (const float4*)(cf + (size_t)d * kNP * 16 + (size_t)ch * 16384);
  float4* dst = (float4*)sc;
#pragma unroll
  for (int i = 0; i < 8; ++i) dst[t + i * 256] = src[t + i * 256];
  __syncthreads();

  int wave = t >> 6, lane = t & 63;
  int n = lane & 31, hh = lane >> 5;   // hh = K-half (0: k0-7, 1: k8-15)
  int qbase = d * kNP + qb * 1024 + wave * 256;

  const short one_bf = (short)0x3F80;  // bf16(1.0)
  short8 bfr[8];
  float mn[8];
#pragma unroll
  for (int i = 0; i < 8; ++i) {
    float4 P = pts[qbase + i * 32 + n];
    unsigned short xh = f2bf(P.x), yh = f2bf(P.y), zh = f2bf(P.z);
    unsigned short xl = f2bf(P.x - bf2f(xh));
    unsigned short yl = f2bf(P.y - bf2f(yh));
    unsigned short zl = f2bf(P.z - bf2f(zh));
    short8 b;
    if (hh == 0)
      b = (short8){(short)xh, (short)xh, (short)xl, (short)yh,
                   (short)yh, (short)yl, (short)zh, (short)zh};
    else
      b = (short8){(short)zl, one_bf, one_bf, one_bf, 0, 0, 0, 0};
    bfr[i] = b;
    mn[i] = 3.0e38f;
  }

  floatx16 zf;
#pragma unroll
  for (int z = 0; z < 16; ++z) zf[z] = 0.0f;

  const short8* scp = ((const short8*)sc) + lane;  // lane's 16B slice
#pragma unroll 2
  for (int ctile = 0; ctile < CCH / 32; ++ctile) {
    // A: candidate m = lane&31, K-half = lane>>5 (layout HW-verified m74/m101)
    short8 a = scp[ctile * 64];
#pragma unroll
    for (int i = 0; i < 8; ++i) {
      floatx16 dr = __builtin_amdgcn_mfma_f32_32x32x16_bf16(a, bfr[i], zf, 0, 0, 0);
      // D col = lane&31 = query n; 16 regs + xor-32 partner cover all 32 rows.
      float m = mn[i];
#pragma unroll
      for (int rr = 0; rr < 16; ++rr) m = fminf(m, dr[rr]);
      mn[i] = m;
    }
  }

#pragma unroll
  for (int i = 0; i < 8; ++i) {
    float m = mn[i];
    m = fminf(m, __shfl_xor(m, 32));
    if (lane < 32) {
      unsigned bb = __float_as_uint(m);
      unsigned e = (bb & 0x80000000u) ? ~bb : (bb | 0x80000000u);
      atomicMin(&minarr[qbase + i * 32 + lane], e);
    }
  }

  // ---- last block of this dir does the per-dir reduction ----
  __threadfence();              // release our atomics (all threads)
  __syncthreads();
  if (t == 0) s_ticket = atomicAdd(&dcnt[d], 1u);
  __syncthreads();
  if (s_ticket != 63u) return;
  __threadfence();              // acquire other blocks' atomics

  float wsum = 0.0f, msum = 0.0f;
#pragma unroll 4
  for (int j = 0; j < 32; ++j) {
    int k = j * 256 + t;
    unsigned u = __hip_atomic_load(&minarr[(size_t)d * kNP + k],
                                   __ATOMIC_RELAXED, __HIP_MEMORY_SCOPE_AGENT);
    unsigned bb = (u & 0x80000000u) ? (u ^ 0x80000000u) : ~u;
    float mnv = __uint_as_float(bb);
    float4 P = pts[(size_t)d * kNP + k];
    if (P.w < 16384.0f) {
      wsum += P.w + mnv;
      msum += 1.0f;
    }
  }
#pragma unroll
  for (int off = 32; off; off >>= 1) {
    wsum += __shfl_down(wsum, off);
    msum += __shfl_down(msum, off);
  }
  if ((t & 63) == 0) { sw[t >> 6] = wsum; sm[t >> 6] = msum; }
  __syncthreads();
  if (t == 0) {
    float ws_ = sw[0] + sw[1] + sw[2] + sw[3];
    float ms_ = sm[0] + sm[1] + sm[2] + sm[3];
    mval[d] = ws_ / fmaxf(ms_, 1.0f);
    __threadfence();            // release mval[d]
    s_ticket = atomicAdd(acnt, 1u);
  }
  __syncthreads();
  if (s_ticket != (unsigned)(kDirs - 1)) return;
  // ---- very last block combines 16 dir values into the 12 outputs ----
  if (t == 0) {
    __threadfence();            // acquire mval[]
    float mv[kDirs];
    for (int dd = 0; dd < kDirs; ++dd)
      mv[dd] = __hip_atomic_load(&mval[dd], __ATOMIC_RELAXED,
                                 __HIP_MEMORY_SCOPE_AGENT);
    for (int s = 0; s < kS; ++s) {
      float acc = 0.0f;
      for (int b = 0; b < kB; ++b) {
        int p = b * kS + s;
        float tens = mv[2 * p] + mv[2 * p + 1];
        out[kS + s * kB + b] = tens;
        acc += tens;
      }
      out[s] = acc * (1.0f / kB);
    }
  }
}

extern "C" void kernel_launch(void* const* d_in, const int* in_sizes, int n_in,
                              void* d_out, int out_size, void* d_ws, size_t ws_size,
                              hipStream_t stream) {
  const float* rv = (const float*)d_in[0];
  const float* tgt = (const float*)d_in[1];
  float* ws = (float*)d_ws;
  unsigned short* cf = (unsigned short*)ws;
  float4* pts = (float4*)(ws + OFF_PTS);
  unsigned* minarr = (unsigned*)(ws + OFF_MIN);
  float* mval = ws + OFF_MVAL;
  unsigned* dcnt = (unsigned*)(ws + OFF_DCNT);
  unsigned* acnt = (unsigned*)(ws + OFF_ACNT);
  float* out = (float*)d_out;

  hipLaunchKernelGGL(prep_kernel, dim3(kPairs * kNP / 256), dim3(256), 0, stream,
                     rv, tgt, cf, pts, minarr, mval, dcnt, acnt);
  hipLaunchKernelGGL(nn_kernel, dim3(kDirs * NQB * NCC), dim3(256), 0, stream,
                     cf, pts, minarr, mval, dcnt, acnt, out);
}